// Round 4
// baseline (6604.414 us; speedup 1.0000x reference)
//
#include <hip/hip_runtime.h>

#define TT 512
#define HH 50

__device__ __forceinline__ float sigf(float x) {
    return 1.0f / (1.0f + __expf(-x));
}
__device__ __forceinline__ float tanhfast(float x) {
    // tanh(x) = 1 - 2/(e^{2x}+1); exact limits at +-inf, branch-free
    return 1.0f - 2.0f / (__expf(2.0f * x) + 1.0f);
}

// One 50-length dot product, 2 accumulator chains (dep chain ~25 FMA).
// hp is an LDS pointer, uniform across the wave (broadcast reads, conflict-free).
__device__ __forceinline__ float dot50(const float (&w)[HH], const float* hp, float a) {
    float b = 0.0f;
#pragma unroll
    for (int q = 0; q < 12; ++q) {
        float4 h4 = *reinterpret_cast<const float4*>(&hp[4 * q]);
        a = fmaf(h4.x, w[4 * q + 0], a);
        b = fmaf(h4.y, w[4 * q + 1], b);
        a = fmaf(h4.z, w[4 * q + 2], a);
        b = fmaf(h4.w, w[4 * q + 3], b);
    }
    float2 h2 = *reinterpret_cast<const float2*>(&hp[48]);
    a = fmaf(h2.x, w[48], a);
    b = fmaf(h2.y, w[49], b);
    return a + b;
}

// One block = one batch element, 12 waves = 3 matrices x 4 gates:
//   p = wid>>2: 0 -> W_hh0 (layer0 recurrent), 1 -> W_ih1 (layer1 input),
//               2 -> W_hh1 (layer1 recurrent);  g = wid&3: gate (i,f,g,o).
// Lane j of wave (p,g) holds row (g*50+j): 50 stationary weights/lane.
// ~75-90 VGPRs total -> fits the 6-waves/EU arch-VGPR class; the loop-top
// asm pins make per-tick reload-from-global illegal and an AGPR home
// (accvgpr round-trip per tick) unprofitable. Escape hatch = scratch spill,
// which would show as MBs in WRITE_SIZE (tripwire; currently ~128 KB).
// Pipeline skew (validated rounds 2-3, absmax=0): p0 step t=tau, p1 computes
// xg1 at tau for step tau-1, p2 step t=tau-2. Two barriers per tick.
__global__ __launch_bounds__(768)
void lstm2_pipeline12_kernel(const float* __restrict__ x,
                             const float* __restrict__ W_ih0, const float* __restrict__ W_hh0,
                             const float* __restrict__ b_ih0, const float* __restrict__ b_hh0,
                             const float* __restrict__ W_ih1, const float* __restrict__ W_hh1,
                             const float* __restrict__ b_ih1, const float* __restrict__ b_hh1,
                             const float* __restrict__ W1, const float* __restrict__ b1,
                             const float* __restrict__ W2, const float* __restrict__ b2,
                             const float* __restrict__ W3, const float* __restrict__ b3,
                             float* __restrict__ out)
{
    const int b    = blockIdx.x;
    const int tid  = threadIdx.x;
    const int wid  = tid >> 6;     // 0..11
    const int p    = wid >> 2;     // matrix: 0=W_hh0, 1=W_ih1, 2=W_hh1
    const int g    = wid & 3;      // gate: 0=i, 1=f, 2=g, 3=o
    const int lane = tid & 63;
    const int js   = (lane < HH) ? lane : 0;   // clamped unit index
    const bool act = (lane < HH);

    __shared__ __align__(16) float h0[52];         // layer0 hidden
    __shared__ __align__(16) float h1[52];         // layer1 hidden
    __shared__ __align__(16) float G0[4][52];      // layer0 gate pre-activations [gate][unit]
    __shared__ __align__(16) float G2[4][52];      // layer1 gate pre-activations
    __shared__ __align__(16) float Bx[2][4][52];   // xg1 double buffer [buf][gate][unit]
    __shared__ float D1[32];
    __shared__ float D2[16];

    if (tid < 52) { h0[tid] = 0.0f; h1[tid] = 0.0f; }

    // --- Stationary weights: lane j of wave (p,g) holds row g*50+j ---
    const float* Wm = (p == 0) ? W_hh0 : (p == 1) ? W_ih1 : W_hh1;
    const int row = g * HH + js;
    float w[HH];
#pragma unroll
    for (int k = 0; k < HH; ++k)
        w[k] = Wm[row * HH + k];

    float bias = (p == 0) ? (b_ih0[row] + b_hh0[row]) : (p == 1) ? b_ih1[row] : b_hh1[row];
    float wx   = (p == 0) ? W_ih0[row] : 0.0f;

    float c_st = 0.0f;                 // cell state (wave p0g0: layer0, wave p2g0: layer1)
    const float* xrow = x + (size_t)b * TT;
    float x_cur = (p == 0) ? xrow[0] : 0.0f;
    float x_nxt = 0.0f;

    __syncthreads();

    for (int tau = 0; tau < TT + 2; ++tau) {
        // --- Register pins, per iteration: values may not be re-derived from
        // memory (asm output is opaque) and "+v" is the arch-VGPR class, so an
        // AGPR home would cost accvgpr round-trips each tick. Emits 0 instrs.
#pragma unroll
        for (int k = 0; k < HH; ++k)
            asm volatile("" : "+v"(w[k]));
        asm volatile("" : "+v"(bias));
        asm volatile("" : "+v"(wx));

        // ================= M phase: matmuls =================
        if (p == 0) {
            if (tau < TT) {                         // step t = tau, reads h0(t-1)
                if (tau + 1 < TT) x_nxt = xrow[tau + 1];
                float a = dot50(w, h0, fmaf(x_cur, wx, bias));
                if (act) G0[g][lane] = a;
                x_cur = x_nxt;
            }
        } else if (p == 1) {
            if (tau >= 1 && tau <= TT) {            // xg1 for step t = tau-1, reads h0(t)
                float a = dot50(w, h0, bias);
                if (act) Bx[tau & 1][g][lane] = a;
            }
        } else {
            if (tau >= 2) {                         // step t = tau-2, reads h1(t-1), xg1(t)
                float a = dot50(w, h1, bias + Bx[(tau + 1) & 1][g][js]);
                if (act) G2[g][lane] = a;
            }
        }
        __syncthreads();
        // ================= P phase: pointwise =================
        if (g == 0 && act) {
            if (p == 0 && tau < TT) {
                float i = sigf(G0[0][lane]);
                float f = sigf(G0[1][lane]);
                float gg = tanhfast(G0[2][lane]);
                float o = sigf(G0[3][lane]);
                c_st = fmaf(f, c_st, i * gg);
                h0[lane] = o * tanhfast(c_st);
            } else if (p == 2 && tau >= 2) {
                float i = sigf(G2[0][lane]);
                float f = sigf(G2[1][lane]);
                float gg = tanhfast(G2[2][lane]);
                float o = sigf(G2[3][lane]);
                c_st = fmaf(f, c_st, i * gg);
                h1[lane] = o * tanhfast(c_st);
            }
        }
        __syncthreads();
    }

    // --- MLP head on final h1 (in LDS); wave 0 computes, barriers hit by all ---
    if (wid == 0 && lane < 32) {
        float z = b1[lane];
#pragma unroll
        for (int k = 0; k < HH; ++k) z = fmaf(W1[lane * HH + k], h1[k], z);
        D1[lane] = fmaxf(z, 0.0f);
    }
    __syncthreads();
    if (wid == 0 && lane < 16) {
        float z = b2[lane];
#pragma unroll
        for (int k = 0; k < 32; ++k) z = fmaf(W2[lane * 32 + k], D1[k], z);
        D2[lane] = fmaxf(z, 0.0f);
    }
    __syncthreads();
    if (wid == 0 && lane == 0) {
        float z = b3[0];
#pragma unroll
        for (int k = 0; k < 16; ++k) z = fmaf(W3[k], D2[k], z);
        out[b] = z;
    }
}

extern "C" void kernel_launch(void* const* d_in, const int* in_sizes, int n_in,
                              void* d_out, int out_size, void* d_ws, size_t ws_size,
                              hipStream_t stream) {
    const float* x     = (const float*)d_in[0];
    const float* W_ih0 = (const float*)d_in[1];
    const float* W_hh0 = (const float*)d_in[2];
    const float* b_ih0 = (const float*)d_in[3];
    const float* b_hh0 = (const float*)d_in[4];
    const float* W_ih1 = (const float*)d_in[5];
    const float* W_hh1 = (const float*)d_in[6];
    const float* b_ih1 = (const float*)d_in[7];
    const float* b_hh1 = (const float*)d_in[8];
    const float* W1    = (const float*)d_in[9];
    const float* b1    = (const float*)d_in[10];
    const float* W2    = (const float*)d_in[11];
    const float* b2    = (const float*)d_in[12];
    const float* W3    = (const float*)d_in[13];
    const float* b3    = (const float*)d_in[14];

    const int B = in_sizes[0] / TT;   // x is [B, T, 1]

    lstm2_pipeline12_kernel<<<dim3(B), dim3(768), 0, stream>>>(
        x, W_ih0, W_hh0, b_ih0, b_hh0, W_ih1, W_hh1, b_ih1, b_hh1,
        W1, b1, W2, b2, W3, b3, (float*)d_out);
}

// Round 5
// 5179.194 us; speedup vs baseline: 1.2752x; 1.2752x over previous
//
#include <hip/hip_runtime.h>

#define TT 512
#define HH 50

__device__ __forceinline__ float sigf(float x) {
    return 1.0f / (1.0f + __expf(-x));
}
__device__ __forceinline__ float tanhfast(float x) {
    // tanh(x) = 1 - 2/(e^{2x}+1); exact limits at +-inf, branch-free
    return 1.0f - 2.0f / (__expf(2.0f * x) + 1.0f);
}

// 2 parallel 50-length dot products: a_g += sum_k w[g][k] * hp[k]
// hp is an LDS pointer, uniform across the wave (broadcast reads, conflict-free).
__device__ __forceinline__ void dot50x2(const float (&w)[2][HH], const float* hp,
                                        float& a0, float& a1) {
#pragma unroll
    for (int q = 0; q < 12; ++q) {
        float4 h4 = *reinterpret_cast<const float4*>(&hp[4 * q]);
        a0 = fmaf(h4.x, w[0][4 * q + 0], a0);
        a0 = fmaf(h4.y, w[0][4 * q + 1], a0);
        a0 = fmaf(h4.z, w[0][4 * q + 2], a0);
        a0 = fmaf(h4.w, w[0][4 * q + 3], a0);
        a1 = fmaf(h4.x, w[1][4 * q + 0], a1);
        a1 = fmaf(h4.y, w[1][4 * q + 1], a1);
        a1 = fmaf(h4.z, w[1][4 * q + 2], a1);
        a1 = fmaf(h4.w, w[1][4 * q + 3], a1);
    }
    float2 h2 = *reinterpret_cast<const float2*>(&hp[48]);
    a0 = fmaf(h2.x, w[0][48], a0); a0 = fmaf(h2.y, w[0][49], a0);
    a1 = fmaf(h2.x, w[1][48], a1); a1 = fmaf(h2.y, w[1][49], a1);
}

// Fused register pins: 25 simultaneous "+v" operands per asm block.
// Simultaneity forces >=25 co-resident arch VGPRs (round-4's sequential pins
// allowed an AGPR<->VGPR shuttle through ~3 scratch regs); per-tick
// redefinition makes an AGPR home cost 100 reads + 100 writes per tick.
#define PIN25(A, O) asm volatile("" : \
    "+v"(A[O+0]),"+v"(A[O+1]),"+v"(A[O+2]),"+v"(A[O+3]),"+v"(A[O+4]), \
    "+v"(A[O+5]),"+v"(A[O+6]),"+v"(A[O+7]),"+v"(A[O+8]),"+v"(A[O+9]), \
    "+v"(A[O+10]),"+v"(A[O+11]),"+v"(A[O+12]),"+v"(A[O+13]),"+v"(A[O+14]), \
    "+v"(A[O+15]),"+v"(A[O+16]),"+v"(A[O+17]),"+v"(A[O+18]),"+v"(A[O+19]), \
    "+v"(A[O+20]),"+v"(A[O+21]),"+v"(A[O+22]),"+v"(A[O+23]),"+v"(A[O+24]))

// One block = one batch element, 6 waves = 3 pairs:
//   pair p=0: layer0 recurrent (W_hh0), p=1: layer1 input matmul (W_ih1),
//   pair p=2: layer1 recurrent (W_hh1).
// Within a pair, wave s=0 owns gates (i,f), s=1 owns gates (g,o): 100 weights/lane.
// __launch_bounds__(384, 3): min 3 waves/EU -> register budget ~170, so a
// ~130-VGPR home for weights+working set is LEGAL (round 3's waves_per_eu(4,4)
// made it illegal at 128 and forced the AGPR shuttle).
// Tripwires: VGPR_Count <= 64 => allocator still AGPR-homing (pivot to MFMA);
// WRITE_SIZE in MBs => scratch spill.
__global__ __launch_bounds__(384, 3)
void lstm2_pipeline6_kernel(const float* __restrict__ x,
                            const float* __restrict__ W_ih0, const float* __restrict__ W_hh0,
                            const float* __restrict__ b_ih0, const float* __restrict__ b_hh0,
                            const float* __restrict__ W_ih1, const float* __restrict__ W_hh1,
                            const float* __restrict__ b_ih1, const float* __restrict__ b_hh1,
                            const float* __restrict__ W1, const float* __restrict__ b1,
                            const float* __restrict__ W2, const float* __restrict__ b2,
                            const float* __restrict__ W3, const float* __restrict__ b3,
                            float* __restrict__ out)
{
    const int b    = blockIdx.x;
    const int tid  = threadIdx.x;
    const int wid  = tid >> 6;     // 0..5
    const int p    = wid >> 1;     // matrix: 0=W_hh0, 1=W_ih1, 2=W_hh1
    const int s    = wid & 1;      // gate half: 0 -> (i,f), 1 -> (g,o)
    const int lane = tid & 63;
    const int js   = (lane < HH) ? lane : 0;   // clamped unit index
    const bool act = (lane < HH);

    __shared__ __align__(16) float h0[52];         // layer0 hidden
    __shared__ __align__(16) float h1[52];         // layer1 hidden
    __shared__ __align__(16) float G0[4][52];      // layer0 gate pre-activations [gate][unit]
    __shared__ __align__(16) float G2[4][52];      // layer1 gate pre-activations
    __shared__ __align__(16) float Bx[2][4][52];   // xg1 double buffer [buf][gate][unit]
    __shared__ float D1[32];
    __shared__ float D2[16];

    if (tid < 52) { h0[tid] = 0.0f; h1[tid] = 0.0f; }

    // --- Stationary weights: lane j of wave (p,s) holds rows {2s*50+j, (2s+1)*50+j} ---
    const float* Wm = (p == 0) ? W_hh0 : (p == 1) ? W_ih1 : W_hh1;
    float w[2][HH];
#pragma unroll
    for (int g = 0; g < 2; ++g) {
        const int row = (2 * s + g) * HH + js;
#pragma unroll
        for (int k = 0; k < HH; ++k)
            w[g][k] = Wm[row * HH + k];
    }

    float bias[2], wx[2];
#pragma unroll
    for (int g = 0; g < 2; ++g) {
        const int r = (2 * s + g) * HH + js;
        bias[g] = (p == 0) ? (b_ih0[r] + b_hh0[r]) : (p == 1) ? b_ih1[r] : b_hh1[r];
        wx[g]   = (p == 0) ? W_ih0[r] : 0.0f;
    }

    float c_st = 0.0f;                 // cell state (p0s0: layer0, p2s0: layer1)
    const float* xrow = x + (size_t)b * TT;
    float x_cur = (p == 0) ? xrow[0] : 0.0f;
    float x_nxt = 0.0f;

    __syncthreads();

    for (int tau = 0; tau < TT + 2; ++tau) {
        // Per-tick fused pins (see PIN25 comment). Emits zero instructions.
        PIN25(w[0], 0); PIN25(w[0], 25);
        PIN25(w[1], 0); PIN25(w[1], 25);
        asm volatile("" : "+v"(bias[0]), "+v"(bias[1]), "+v"(wx[0]), "+v"(wx[1]));

        // ================= M phase: matmuls =================
        if (p == 0) {
            if (tau < TT) {                         // step t = tau, reads h0(t-1)
                if (tau + 1 < TT) x_nxt = xrow[tau + 1];
                float a0 = fmaf(x_cur, wx[0], bias[0]);
                float a1 = fmaf(x_cur, wx[1], bias[1]);
                dot50x2(w, h0, a0, a1);
                if (act) { G0[2 * s][lane] = a0; G0[2 * s + 1][lane] = a1; }
                x_cur = x_nxt;
            }
        } else if (p == 1) {
            if (tau >= 1 && tau <= TT) {            // xg1 for step t = tau-1, reads h0(t)
                float a0 = bias[0], a1 = bias[1];
                dot50x2(w, h0, a0, a1);
                if (act) {
                    Bx[tau & 1][2 * s][lane]     = a0;
                    Bx[tau & 1][2 * s + 1][lane] = a1;
                }
            }
        } else {
            if (tau >= 2) {                         // step t = tau-2, reads h1(t-1), xg1(t)
                const int buf = (tau + 1) & 1;
                float a0 = bias[0] + Bx[buf][2 * s][js];
                float a1 = bias[1] + Bx[buf][2 * s + 1][js];
                dot50x2(w, h1, a0, a1);
                if (act) { G2[2 * s][lane] = a0; G2[2 * s + 1][lane] = a1; }
            }
        }
        __syncthreads();
        // ================= P phase: pointwise =================
        if (s == 0 && act) {
            if (p == 0 && tau < TT) {
                float i = sigf(G0[0][lane]);
                float f = sigf(G0[1][lane]);
                float g = tanhfast(G0[2][lane]);
                float o = sigf(G0[3][lane]);
                c_st = fmaf(f, c_st, i * g);
                h0[lane] = o * tanhfast(c_st);
            } else if (p == 2 && tau >= 2) {
                float i = sigf(G2[0][lane]);
                float f = sigf(G2[1][lane]);
                float g = tanhfast(G2[2][lane]);
                float o = sigf(G2[3][lane]);
                c_st = fmaf(f, c_st, i * g);
                h1[lane] = o * tanhfast(c_st);
            }
        }
        __syncthreads();
    }

    // --- MLP head on final h1 (in LDS); wave 0 computes, barriers hit by all ---
    if (wid == 0 && lane < 32) {
        float z = b1[lane];
#pragma unroll
        for (int k = 0; k < HH; ++k) z = fmaf(W1[lane * HH + k], h1[k], z);
        D1[lane] = fmaxf(z, 0.0f);
    }
    __syncthreads();
    if (wid == 0 && lane < 16) {
        float z = b2[lane];
#pragma unroll
        for (int k = 0; k < 32; ++k) z = fmaf(W2[lane * 32 + k], D1[k], z);
        D2[lane] = fmaxf(z, 0.0f);
    }
    __syncthreads();
    if (wid == 0 && lane == 0) {
        float z = b3[0];
#pragma unroll
        for (int k = 0; k < 16; ++k) z = fmaf(W3[k], D2[k], z);
        out[b] = z;
    }
}

extern "C" void kernel_launch(void* const* d_in, const int* in_sizes, int n_in,
                              void* d_out, int out_size, void* d_ws, size_t ws_size,
                              hipStream_t stream) {
    const float* x     = (const float*)d_in[0];
    const float* W_ih0 = (const float*)d_in[1];
    const float* W_hh0 = (const float*)d_in[2];
    const float* b_ih0 = (const float*)d_in[3];
    const float* b_hh0 = (const float*)d_in[4];
    const float* W_ih1 = (const float*)d_in[5];
    const float* W_hh1 = (const float*)d_in[6];
    const float* b_ih1 = (const float*)d_in[7];
    const float* b_hh1 = (const float*)d_in[8];
    const float* W1    = (const float*)d_in[9];
    const float* b1    = (const float*)d_in[10];
    const float* W2    = (const float*)d_in[11];
    const float* b2    = (const float*)d_in[12];
    const float* W3    = (const float*)d_in[13];
    const float* b3    = (const float*)d_in[14];

    const int B = in_sizes[0] / TT;   // x is [B, T, 1]

    lstm2_pipeline6_kernel<<<dim3(B), dim3(384), 0, stream>>>(
        x, W_ih0, W_hh0, b_ih0, b_hh0, W_ih1, W_hh1, b_ih1, b_hh1,
        W1, b1, W2, b2, W3, b3, (float*)d_out);
}